// Round 7
// baseline (4093.457 us; speedup 1.0000x reference)
//
#include <hip/hip_runtime.h>
#include <stdint.h>

#define A_N 384
#define F_N 128
#define C_N 32
#define H_N 512
#define LN_EPS 1e-5f

typedef unsigned short u16;

// ---- scratch in static device memory (d_ws unused entirely) ----
__device__ float g_left[A_N * C_N];
__device__ float g_right[A_N * C_N];
__device__ float g_M[A_N * F_N * C_N];     // [b][f][c] fp32

__device__ __forceinline__ float b2f(u16 u) {
    union { float f; uint32_t i; } v; v.i = ((uint32_t)u) << 16; return v.f;
}
// dtype-adaptive input load: isbf ? bf16[idx] : fp32[idx]
__device__ __forceinline__ float ld(const void* p, int idx, bool isbf) {
    if (isbf) return b2f(((const u16*)p)[idx]);
    return ((const float*)p)[idx];
}
__device__ __forceinline__ bool probe_bf16(const void* node_mask) {
    return ((const u16*)node_mask)[0] == 0x3F80u;   // 1.0 as bf16; fp32 LE low half is 0x0000
}

// ---------------- K1: node LN + left/right projections ----------------
__global__ void k_leftright(const void* __restrict__ node_vec, const void* __restrict__ node_mask,
                            const void* __restrict__ op_scale, const void* __restrict__ op_bias,
                            const void* __restrict__ w_left, const void* __restrict__ b_left,
                            const void* __restrict__ w_right, const void* __restrict__ b_right) {
    bool isbf = probe_bf16(node_mask);
    int a = blockIdx.x;
    int f = threadIdx.x;            // 128 threads = 2 waves
    __shared__ float sAct[F_N];
    __shared__ float sRed[4];
    float x = ld(node_vec, a * F_N + f, isbf);
    float s1 = x, s2 = x * x;
    for (int o = 1; o < 64; o <<= 1) { s1 += __shfl_xor(s1, o); s2 += __shfl_xor(s2, o); }
    int wv = threadIdx.x >> 6;
    if ((threadIdx.x & 63) == 0) { sRed[wv * 2] = s1; sRed[wv * 2 + 1] = s2; }
    __syncthreads();
    float sum = sRed[0] + sRed[2], sq = sRed[1] + sRed[3];
    float mu = sum * (1.0f / F_N);
    float var = sq * (1.0f / F_N) - mu * mu;
    float rs = rsqrtf(var + LN_EPS);
    sAct[f] = (x - mu) * rs * ld(op_scale, f, isbf) + ld(op_bias, f, isbf);
    __syncthreads();
    if (threadIdx.x < 64) {
        int c = threadIdx.x & 31;
        bool isL = threadIdx.x < 32;
        const void* W = isL ? w_left : w_right;
        const void* B = isL ? b_left : b_right;
        float acc = ld(B, c, isbf);
        for (int ff = 0; ff < F_N; ff++) acc += sAct[ff] * ld(W, ff * C_N + c, isbf);
        acc *= ld(node_mask, a, isbf);
        float* dst = isL ? g_left : g_right;
        dst[a * C_N + c] = acc;   // row-major [a][c]
    }
}

// ---------------- K2: M[b][f][c] = sum_d right[b,d] * w_out[(c*32+d), f] ----------------
__global__ void k_M(const void* __restrict__ w_out, const void* __restrict__ node_mask) {
    bool isbf = probe_bf16(node_mask);
    int b = blockIdx.x;
    int f = threadIdx.x;            // 128 threads
    __shared__ float sR[C_N];
    if (f < C_N) sR[f] = g_right[b * C_N + f];
    __syncthreads();
    for (int c = 0; c < C_N; c++) {
        float acc = 0.f;
        for (int d = 0; d < C_N; d++) acc += sR[d] * ld(w_out, (c * C_N + d) * F_N + f, isbf);
        g_M[(b * F_N + f) * C_N + c] = acc;
    }
}

// ---------------- K3: edge = edge_vec + op + b_out -> d_out (FP32) ----------------
// Faithful einsum: OUT[a,b,f] = edge_vec[a,b,f] + sum_c left[a,c]*M[b,f,c] + b_out[f]
__global__ void k_edge_naive(const void* __restrict__ edge_vec, const void* __restrict__ b_out,
                             const void* __restrict__ node_mask, float* __restrict__ EO) {
    bool isbf = probe_bf16(node_mask);
    int a = blockIdx.x;
    int b0 = blockIdx.y * 16;
    int f = threadIdx.x;            // 128 threads
    __shared__ float sL[C_N];
    if (f < C_N) sL[f] = g_left[a * C_N + f];
    __syncthreads();
    float bout = ld(b_out, f, isbf);
    for (int bb = 0; bb < 16; bb++) {
        int b = b0 + bb;
        const float* mrow = g_M + ((size_t)b * F_N + f) * C_N;
        float acc = bout;
        #pragma unroll
        for (int c = 0; c < C_N; c++) acc += sL[c] * mrow[c];
        size_t rG = (size_t)a * A_N + b;
        EO[rG * F_N + f] = ld(edge_vec, (int)(rG * F_N + f), isbf) + acc;
    }
}

// ---------------- K4: out = E + relu(LN(E)@W1+b1)@W2+b2, scalar-naive, in-place FP32 ----------------
__global__ void k_mlp_naive(float* __restrict__ EO,
                            const void* __restrict__ w_t1, const void* __restrict__ b_t1,
                            const void* __restrict__ w_t2, const void* __restrict__ b_t2,
                            const void* __restrict__ tr_scale, const void* __restrict__ tr_bias,
                            const void* __restrict__ node_mask) {
    bool isbf = probe_bf16(node_mask);
    int tid = threadIdx.x;          // 128 threads = 2 waves; thread tid <-> feature f = tid
    __shared__ float sX[F_N];
    __shared__ float sH[H_N];
    __shared__ float sRed[4];
    float scl = ld(tr_scale, tid, isbf);
    float bia = ld(tr_bias, tid, isbf);
    float b2v = ld(b_t2, tid, isbf);
    size_t rowBase = (size_t)blockIdx.x * 16;

    for (int r = 0; r < 16; r++) {
        size_t row = rowBase + r;
        float e = EO[row * F_N + tid];
        // LayerNorm over the 128 features (2 waves)
        float s1 = e, s2 = e * e;
        for (int o = 1; o < 64; o <<= 1) { s1 += __shfl_xor(s1, o); s2 += __shfl_xor(s2, o); }
        int wv = tid >> 6;
        if ((tid & 63) == 0) { sRed[wv * 2] = s1; sRed[wv * 2 + 1] = s2; }
        __syncthreads();
        float sum = sRed[0] + sRed[2], sq = sRed[1] + sRed[3];
        float mu = sum * (1.0f / F_N);
        float var = sq * (1.0f / F_N) - mu * mu;
        float rs = rsqrtf(var + LN_EPS);
        sX[tid] = (e - mu) * rs * scl + bia;
        __syncthreads();
        // phase 1: hidden units, thread handles j = tid, tid+128, tid+256, tid+384
        #pragma unroll
        for (int jj = 0; jj < 4; jj++) {
            int j = jj * F_N + tid;
            float acc = ld(b_t1, j, isbf);
            for (int k = 0; k < F_N; k++) acc += sX[k] * ld(w_t1, k * H_N + j, isbf);
            sH[j] = fmaxf(acc, 0.f);
        }
        __syncthreads();
        // phase 2: output feature f = tid
        float t = b2v;
        for (int j = 0; j < H_N; j++) t += sH[j] * ld(w_t2, j * F_N + tid, isbf);
        EO[row * F_N + tid] = e + t;
        __syncthreads();   // protect sX/sH/sRed for next row
    }
}

extern "C" void kernel_launch(void* const* d_in, const int* in_sizes, int n_in,
                              void* d_out, int out_size, void* d_ws, size_t ws_size,
                              hipStream_t stream) {
    const void* node_vec  = d_in[0];
    const void* edge_vec  = d_in[1];
    const void* node_mask = d_in[2];
    // d_in[3] edge_mask: unused by reference
    const void* op_scale  = d_in[4];
    const void* op_bias   = d_in[5];
    const void* w_left    = d_in[6];
    const void* b_left    = d_in[7];
    const void* w_right   = d_in[8];
    const void* b_right   = d_in[9];
    const void* w_out     = d_in[10];
    const void* b_out     = d_in[11];
    const void* tr_scale  = d_in[12];
    const void* tr_bias   = d_in[13];
    const void* w_t1      = d_in[14];
    const void* b_t1      = d_in[15];
    const void* w_t2      = d_in[16];
    const void* b_t2      = d_in[17];
    float* out = (float*)d_out;     // reference output dtype is float32
    (void)d_ws; (void)ws_size;      // scratch lives in __device__ globals

    hipLaunchKernelGGL(k_leftright, dim3(A_N), dim3(128), 0, stream,
                       node_vec, node_mask, op_scale, op_bias,
                       w_left, b_left, w_right, b_right);
    hipLaunchKernelGGL(k_M, dim3(A_N), dim3(128), 0, stream, w_out, node_mask);
    hipLaunchKernelGGL(k_edge_naive, dim3(A_N, 24), dim3(128), 0, stream,
                       edge_vec, b_out, node_mask, out);
    hipLaunchKernelGGL(k_mlp_naive, dim3((A_N * A_N) / 16), dim3(128), 0, stream,
                       out, w_t1, b_t1, w_t2, b_t2, tr_scale, tr_bias, node_mask);
}